// Round 3
// baseline (381.239 us; speedup 1.0000x reference)
//
#include <hip/hip_runtime.h>
#include <math.h>

#define B_TOTAL 1048576
#define N_IMG   4096
#define EMB     64
#define CHUNK   512                  // rows per block in partial pass
#define NBLK    (B_TOTAL / CHUNK)    // 2048 blocks -> 8 blocks/CU, 32 waves/CU

// ws layout (floats):
//   [0      .. 4095]  d[n]    (softmax denominators, atomically accumulated)
//   [4096   .. 8191]  num[n]  (weighted-value numerators)
//   [8192   .. 8255]  u[e] = sum_h w_value[e][h]*w_out[h]
//   [8256]            c    = b_value@w_out + b_out
//   [8257]            bout = b_out

// raw ds_swizzle xor-butterfly within a 16-lane group (masks 1,2,4,8 never
// cross the 16-lane boundary; pattern = (xor<<10)|0x1F per cdna4_isa.md)
#define SWZ_ADD(x, imm) \
    (x) += __int_as_float(__builtin_amdgcn_ds_swizzle(__float_as_int(x), (imm)))

__global__ void init_kernel(const float* __restrict__ w_value,
                            const float* __restrict__ b_value,
                            const float* __restrict__ w_out,
                            const float* __restrict__ b_out,
                            float* __restrict__ ws) {
    int t = blockIdx.x * blockDim.x + threadIdx.x;
    if (t < 2 * N_IMG) {
        ws[t] = 0.f;                      // zero d[] and num[] (ws is poisoned)
    } else if (t < 2 * N_IMG + EMB) {
        int e = t - 2 * N_IMG;
        float acc = 0.f;
        for (int h = 0; h < EMB; ++h) acc += w_value[e * EMB + h] * w_out[h];
        ws[2 * N_IMG + e] = acc;          // u[e]
        if (e == 0) {
            float c = 0.f;
            for (int h = 0; h < EMB; ++h) c += b_value[h] * w_out[h];
            ws[2 * N_IMG + EMB]     = c + b_out[0];   // c
            ws[2 * N_IMG + EMB + 1] = b_out[0];       // bout
        }
    }
}

__global__ __launch_bounds__(256, 8) void partial_kernel(
    const float* __restrict__ emb,
    const int*   __restrict__ ids,
    const float* __restrict__ w_attn,
    const float* __restrict__ ws,
    float*       __restrict__ d_acc,     // ws[0..4095]
    float*       __restrict__ num_acc) { // ws[4096..8191]
    const int tid  = threadIdx.x;
    const int lane = tid & 15;           // lane within 16-lane group
    const int grp  = tid >> 4;           // 16 groups per block
    const int base = blockIdx.x * CHUNK;

    const float4 wa = reinterpret_cast<const float4*>(w_attn)[lane];
    const float4 uu = reinterpret_cast<const float4*>(ws + 2 * N_IMG)[lane];

    int   r       = base + grp;
    int   cur_id  = ids[r];              // group-uniform (broadcast load)
    float acc_d   = 0.f;                 // replicated across the 16 lanes
    float acc_num = 0.f;                 // per-lane PARTIAL of numerator

    auto flush = [&]() {
        float nsum = acc_num;            // reduce the per-lane partials now
        SWZ_ADD(nsum, 0x041F);           // xor 1
        SWZ_ADD(nsum, 0x081F);           // xor 2
        SWZ_ADD(nsum, 0x101F);           // xor 4
        SWZ_ADD(nsum, 0x201F);           // xor 8
        if (lane == 0) {
            atomicAdd(&d_acc[cur_id],   acc_d);
            atomicAdd(&num_acc[cur_id], nsum);
        }
    };

    #pragma unroll 4
    for (int i = 0; i < CHUNK / 16; ++i, r += 16) {
        const float4 e4 = reinterpret_cast<const float4*>(emb + (size_t)r * EMB)[lane];
        const int rid = ids[r];          // group-uniform; non-decreasing over i
        float s = e4.x * wa.x + e4.y * wa.y + e4.z * wa.z + e4.w * wa.w;
        float v = e4.x * uu.x + e4.y * uu.y + e4.z * uu.z + e4.w * uu.w;
        // full score: butterfly over the 16-lane group (s only; v stays partial)
        SWZ_ADD(s, 0x041F);
        SWZ_ADD(s, 0x081F);
        SWZ_ADD(s, 0x101F);
        SWZ_ADD(s, 0x201F);
        if (rid != cur_id) {             // group-uniform branch, rare
            flush();
            acc_d = 0.f; acc_num = 0.f; cur_id = rid;
        }
        const float e = __expf(s);       // max-free: |s| <~ 4, exact-safe in fp32
        acc_d   += e;
        acc_num += e * v;
    }
    flush();
}

// Fused finalize + scatter: depends only on ws (partial's output); computes
// r = num/d + c on the fly per element (d,num live in 32 KB of L2).
__global__ __launch_bounds__(256) void finalize_scatter_kernel(
    const int*   __restrict__ ids,
    const float* __restrict__ ws,
    float*       __restrict__ out) {
    const int gid = blockIdx.x * blockDim.x + threadIdx.x;
    const float c    = ws[2 * N_IMG + EMB];
    const float bout = ws[2 * N_IMG + EMB + 1];

    if (gid < N_IMG) {                    // image-level outputs
        const float d   = ws[gid];
        const float num = ws[N_IMG + gid];
        const float rv  = (d != 0.f) ? (num / d + c) : bout;
        out[(size_t)B_TOTAL + gid]         = rv;        // r_images
        out[(size_t)B_TOTAL + N_IMG + gid] = (float)gid; // unique_ids
    }

    // reflection-level outputs: 4 per thread
    const int4 id4 = reinterpret_cast<const int4*>(ids)[gid];
    float4 o;
    o.x = ws[N_IMG + id4.x] / ws[id4.x] + c;
    o.y = ws[N_IMG + id4.y] / ws[id4.y] + c;
    o.z = ws[N_IMG + id4.z] / ws[id4.z] + c;
    o.w = ws[N_IMG + id4.w] / ws[id4.w] + c;
    reinterpret_cast<float4*>(out)[gid] = o;
}

extern "C" void kernel_launch(void* const* d_in, const int* in_sizes, int n_in,
                              void* d_out, int out_size, void* d_ws, size_t ws_size,
                              hipStream_t stream) {
    const float* emb     = (const float*)d_in[0];
    const int*   ids     = (const int*)  d_in[1];
    const float* w_attn  = (const float*)d_in[2];
    // d_in[3] = b_attn: cancels inside the segment softmax, unused
    const float* w_value = (const float*)d_in[4];
    const float* b_value = (const float*)d_in[5];
    const float* w_out   = (const float*)d_in[6];
    const float* b_out   = (const float*)d_in[7];
    float* out = (float*)d_out;
    float* ws  = (float*)d_ws;

    init_kernel<<<(2 * N_IMG + EMB + 255) / 256, 256, 0, stream>>>(
        w_value, b_value, w_out, b_out, ws);
    partial_kernel<<<NBLK, 256, 0, stream>>>(
        emb, ids, w_attn, ws, ws, ws + N_IMG);
    finalize_scatter_kernel<<<B_TOTAL / (256 * 4), 256, 0, stream>>>(
        ids, ws, out);
}